// Round 16
// baseline (562.263 us; speedup 1.0000x reference)
//
#include <hip/hip_runtime.h>

#define T_STEPS 256
#define BATCH   2048
#define HID     128
#define BH      (BATCH * HID)

typedef short short8  __attribute__((ext_vector_type(8)));
typedef short short4v __attribute__((ext_vector_type(4)));
typedef float float4v __attribute__((ext_vector_type(4)));

__device__ __forceinline__ unsigned short f2bf(float f) {
    unsigned int u = __builtin_bit_cast(unsigned int, f);
    u += 0x7fffu + ((u >> 16) & 1u);
    return (unsigned short)(u >> 16);
}
__device__ __forceinline__ float bf2f(unsigned short b) {
    unsigned int u = ((unsigned int)b) << 16;
    return __builtin_bit_cast(float, u);
}

#if __has_builtin(__builtin_amdgcn_exp2f)
#define EXP2F(x) __builtin_amdgcn_exp2f(x)
#else
#define EXP2F(x) exp2f(x)
#endif
__device__ __forceinline__ float sigf(float x) {
    return __builtin_amdgcn_rcpf(1.0f + EXP2F(x * -1.442695041f));
}
__device__ __forceinline__ float tanh_fast(float x) {
    return 2.0f * __builtin_amdgcn_rcpf(1.0f + EXP2F(x * -2.885390082f)) - 1.0f;
}

// Raw barrier without the vmcnt(0) drain of __syncthreads().
__device__ __forceinline__ void block_sync_lds() {
    asm volatile("s_waitcnt lgkmcnt(0)" ::: "memory");
    __builtin_amdgcn_s_barrier();
    __builtin_amdgcn_sched_barrier(0);
}

// h buffer: [8 rows][256 B], XOR-swizzled, 16-B granule.
__device__ __forceinline__ int lposH(int row, int off) {
    return row * 256 + (off ^ ((row & 7) << 4));
}
// x slot (L1/2): [16 rows][256 B]
__device__ __forceinline__ int lposX(int row, int off) {
    return row * 256 + (off ^ ((row & 7) << 4));
}
// x slot (L0): [16 rows][64 B]
__device__ __forceinline__ int lposX0(int row, int off) {
    return row * 64 + (off ^ ((row & 3) << 4));
}
// xg handoff: fp32 [par][q][row2(4)][col(128)][2] — (row0,row0+1) pair = ONE
// b64. Per-32-lane-half bank check: lanes 0-15 (row2=0) claim banks 0-31
// once; lanes 16-31 (row2=2, base multiple of 128B) claim 0-31 once ->
// 2 claims/bank = b64 floor, conflict-free (verified r15: 60M -> 12M).
__device__ __forceinline__ int lposG(int q, int row0, int col) {
    return (q * 4 + (row0 >> 1)) * 1024 + col * 8;
}

__device__ __forceinline__ short8 load_w8(const float* __restrict__ p) {
    float4v a = *reinterpret_cast<const float4v*>(p);
    float4v b = *reinterpret_cast<const float4v*>(p + 4);
    short8 r;
    r[0] = (short)f2bf(a[0]); r[1] = (short)f2bf(a[1]);
    r[2] = (short)f2bf(a[2]); r[3] = (short)f2bf(a[3]);
    r[4] = (short)f2bf(b[0]); r[5] = (short)f2bf(b[1]);
    r[6] = (short)f2bf(b[2]); r[7] = (short)f2bf(b[3]);
    return r;
}

// LDS: [h0 2K][h1 2K][slot0][slot1][xg 64K]; max (L1/2) = 12288 + 65536
#define LDS_BYTES 77824

// 16-wave producer/consumer LSTM layer phase (block=1024, grid=256, 1/CU).
// 8 gate waves: h-MFMA only, 2 cells/thread; odd steps start with xg
// PREFETCHED in registers (xgwrite stores both parities together, so the
// odd parity is LDS-valid during the preceding even step -> tail prefetch,
// race-free: buffer rewritten 3 barriers later). 8 x waves: slot staging,
// x-projection one pair ahead, xg handoff (b64 pairs), h->global writeback.
template<bool IS_L0, bool WRITE_H, bool FINAL>
__device__ __forceinline__ void lstm_phase(
    unsigned char* a_lds,
    const float* __restrict__ x0,
    const float* __restrict__ Wih,
    const float* __restrict__ Whh,
    const float* __restrict__ bih,
    const float* __restrict__ bhh,
    unsigned short* __restrict__ hbuf,
    const float* __restrict__ Wfc,
    const float* __restrict__ bfc,
    float* __restrict__ out,
    const int tid, const int b0)
{
    constexpr int XKS = IS_L0 ? 1 : 4;               // x K-slices per pair
    constexpr int XRB = IS_L0 ? 64 : 256;            // x slot row bytes
    constexpr int HB  = 2048;
    constexpr int XB  = 16 * XRB;
    constexpr int SL0 = 2 * HB;
    constexpr int SL1 = 2 * HB + XB;
    constexpr int XGB = 2 * HB + 2 * XB;             // xg base
    constexpr int PARS  = 16384;                     // parity stride
    constexpr int PAIRS = 32768;                     // pair stride

    const int lane  = tid & 63;
    const int wv    = tid >> 6;                      // 0..15
    const int t16   = lane & 15;
    const int kgrp8 = (lane >> 4) * 8;
    const int row0  = ((lane >> 4) & 1) * 4 + ((lane >> 5) & 1) * 2;

    // zero h buffers + x slots (h(-1)=0; L0 pad cols stay 0)
    {
        short8 z = {0,0,0,0,0,0,0,0};
        for (int a = tid * 16; a < 2 * HB + 2 * XB; a += 1024 * 16)
            *reinterpret_cast<short8*>(&a_lds[a]) = z;
    }
    __syncthreads();

    if (tid < 512) {
        // ================= GATE WAVES (0-7) =================
        const int jcol = 16 * wv + t16;              // owned column
        const int g2 = t16 >> 2;
        const int hrow = ((g2 & 1) << 2) | ((g2 >> 1) << 1) | (t16 & 1);
        int aoffH[4];
        #pragma unroll
        for (int ks = 0; ks < 4; ++ks)
            aoffH[ks] = lposH(hrow, ks * 64 + kgrp8 * 2);
        const int hwoff0 = lposH(row0,     2 * jcol);
        const int hwoff1 = lposH(row0 + 1, 2 * jcol);
        int xgr[4];
        #pragma unroll
        for (int q = 0; q < 4; ++q)
            xgr[q] = XGB + lposG(q, row0, jcol);

        short8 wfh[4][4];
        #pragma unroll
        for (int q = 0; q < 4; ++q) {
            const int n = 128 * q + jcol;
            #pragma unroll
            for (int ks = 0; ks < 4; ++ks)
                wfh[q][ks] = load_w8(Whh + n * 128 + ks * 32 + kgrp8);
        }

        float cr0 = 0.f, cr1 = 0.f;
        float2 pxg[4];                               // prefetched odd-step xg
        block_sync_lds();               // pairs with x staging barrier
        block_sync_lds();               // pairs with x pair-0 barrier

        // shared core: acc pre-filled with xg; MFMA chain + cell + h write
        auto hcore = [&](const int rb, const int wb, float4v (&acc)[4],
                         const int pre_xgo) {
            short8 hva[4];
            #pragma unroll
            for (int ks = 0; ks < 4; ++ks)
                hva[ks] = *reinterpret_cast<const short8*>(&a_lds[rb + aoffH[ks]]);
            __builtin_amdgcn_s_setprio(1);
            #pragma unroll
            for (int ks = 0; ks < 4; ++ks)
                #pragma unroll
                for (int q = 0; q < 4; ++q)
                    acc[q] = __builtin_amdgcn_mfma_f32_16x16x32_bf16(
                        hva[ks], wfh[q][ks], acc[q], 0, 0, 0);
            __builtin_amdgcn_s_setprio(0);
            const float c0 = sigf(acc[1][0]) * cr0 + sigf(acc[0][0]) * tanh_fast(acc[2][0]);
            const float c1 = sigf(acc[1][1]) * cr1 + sigf(acc[0][1]) * tanh_fast(acc[2][1]);
            cr0 = c0;  cr1 = c1;
            const float h0 = sigf(acc[3][0]) * tanh_fast(c0);
            const float h1 = sigf(acc[3][1]) * tanh_fast(c1);
            unsigned int pk;
            asm("v_cvt_pk_bf16_f32 %0, %1, %2" : "=v"(pk) : "v"(h0), "v"(h1));
            *reinterpret_cast<unsigned short*>(&a_lds[wb + hwoff0]) =
                (unsigned short)(pk & 0xffffu);
            *reinterpret_cast<unsigned short*>(&a_lds[wb + hwoff1]) =
                (unsigned short)(pk >> 16);
            // tail: prefetch next (odd) step's xg — already valid in LDS
            #pragma unroll
            for (int q = 0; q < 4; ++q)
                pxg[q] = *reinterpret_cast<const float2*>(&a_lds[pre_xgo + xgr[q]]);
            block_sync_lds();
        };
        // even step: own xg from LDS (post-barrier), prefetch par1 at tail
        auto hstepE = [&](const int rb, const int wb, const int xgo) {
            float4v acc[4];
            #pragma unroll
            for (int q = 0; q < 4; ++q) {
                const float2 v = *reinterpret_cast<const float2*>(&a_lds[xgo + xgr[q]]);
                acc[q] = float4v{v.x, v.y, v.x, v.y};
            }
            hcore(rb, wb, acc, xgo + PARS);
        };
        // odd step: xg from prefetched registers (no LDS read on the head)
        auto hstepO = [&](const int rb, const int wb, const int nxt_xgo) {
            float4v acc[4];
            #pragma unroll
            for (int q = 0; q < 4; ++q)
                acc[q] = float4v{pxg[q].x, pxg[q].y, pxg[q].x, pxg[q].y};
            hcore(rb, wb, acc, nxt_xgo);   // harmless dummy prefetch target
        };

        for (int mm = 0; mm < T_STEPS / 4; ++mm) {
            hstepE(0,  HB, 0);                 // t=4mm   : buf0 par0; pre par1
            hstepO(HB, 0,  0);                 // t=4mm+1 : uses pxg
            hstepE(0,  HB, PAIRS);             // t=4mm+2 : buf1 par0; pre par1
            hstepO(HB, 0,  PAIRS);             // t=4mm+3 : uses pxg
        }
    } else {
        // ================= X WAVES (8-15) =================
        const int wx = wv - 8;
        const int jX = 16 * wx + t16;                // mirrored column
        const int tid2 = tid - 512;                  // 0..511
        // h->global writeback: 512 thr x 4 B over 8 rows x 256 B
        const int sh_row = tid2 >> 6, sh_c = tid2 & 63;
        const int hroff4 = lposH(sh_row, sh_c * 4);
        const size_t sgoff4 = (size_t)(b0 + sh_row) * HID + sh_c * 2;    // shorts
        // slot staging (L1/2): 512 thr x 8 B over 16 tile-rows x 256 B
        const int sar = tid2 >> 5, sc8 = tid2 & 31;
        const int sb  = (sar & 1) | (((sar >> 3) & 1) << 1) | (((sar >> 2) & 1) << 2);
        const int ss  = (sar >> 1) & 1;
        const int xwoff = lposX(sar, sc8 * 8);
        const size_t xgrow = (size_t)(b0 + sb) * HID + sc8 * 4;          // shorts
        // slot staging (L0): first 256 of tid2, 4 B (2 bf16) each
        const int  tidL = tid2 & 255;
        const bool l0act = tid2 < 256;
        const int  sarL = tidL >> 4, sc16 = tidL & 15;
        const int  sbL = (sarL & 1) | (((sarL >> 3) & 1) << 1) | (((sarL >> 2) & 1) << 2);
        const int  ssL = (sarL >> 1) & 1;
        const bool xvalid = l0act && (sc16 < 12);
        const int  xw0off = lposX0(sarL, sc16 * 4);
        const size_t x0row = (size_t)(b0 + sbL) * (T_STEPS * 24) + sc16 * 2;

        int aoffX[XKS];
        #pragma unroll
        for (int s = 0; s < XKS; ++s)
            aoffX[s] = IS_L0 ? lposX0(t16, kgrp8 * 2)
                             : lposX(t16, s * 64 + kgrp8 * 2);
        int xgw[4];
        #pragma unroll
        for (int q = 0; q < 4; ++q)
            xgw[q] = XGB + lposG(q, row0, jX);

        short8 wfx[4][XKS];
        float  bias[4];
        #pragma unroll
        for (int q = 0; q < 4; ++q) {
            const int n = 128 * q + jX;
            bias[q] = bih[n] + bhh[n];
            if constexpr (IS_L0) {
                if (kgrp8 < 24) wfx[q][0] = load_w8(Wih + n * 24 + kgrp8);
                else { short8 z = {0,0,0,0,0,0,0,0}; wfx[q][0] = z; }
            } else {
                #pragma unroll
                for (int s = 0; s < 4; ++s)
                    wfx[q][s] = load_w8(Wih + n * 128 + s * 32 + kgrp8);
            }
        }

        // prologue staging: SL0 = {x(0),x(1)}, SL1 = {x(2),x(3)}
        if constexpr (!IS_L0) {
            short4v v0 = *reinterpret_cast<const short4v*>(&hbuf[(size_t)(0 + ss) * BH + xgrow]);
            short4v v1 = *reinterpret_cast<const short4v*>(&hbuf[(size_t)(2 + ss) * BH + xgrow]);
            *reinterpret_cast<short4v*>(&a_lds[SL0 + xwoff]) = v0;
            *reinterpret_cast<short4v*>(&a_lds[SL1 + xwoff]) = v1;
        } else if (xvalid) {
            float2 a = *reinterpret_cast<const float2*>(&x0[x0row + (size_t)(0 + ssL) * 24]);
            float2 b = *reinterpret_cast<const float2*>(&x0[x0row + (size_t)(2 + ssL) * 24]);
            unsigned int pa, pb;
            asm("v_cvt_pk_bf16_f32 %0, %1, %2" : "=v"(pa) : "v"(a.x), "v"(a.y));
            asm("v_cvt_pk_bf16_f32 %0, %1, %2" : "=v"(pb) : "v"(b.x), "v"(b.y));
            *reinterpret_cast<unsigned int*>(&a_lds[SL0 + xw0off]) = pa;
            *reinterpret_cast<unsigned int*>(&a_lds[SL1 + xw0off]) = pb;
        }
        block_sync_lds();

        float4v xacc[4];
        auto xinit = [&]() {
            #pragma unroll
            for (int q = 0; q < 4; ++q)
                xacc[q] = float4v{bias[q], bias[q], bias[q], bias[q]};
        };
        auto xmfma2 = [&](const int SLrd, const int s0) {
            short8 a0 = *reinterpret_cast<const short8*>(&a_lds[SLrd + aoffX[s0]]);
            short8 a1 = *reinterpret_cast<const short8*>(&a_lds[SLrd + aoffX[s0 + 1]]);
            #pragma unroll
            for (int q = 0; q < 4; ++q)
                xacc[q] = __builtin_amdgcn_mfma_f32_16x16x32_bf16(
                    a0, wfx[q][s0], xacc[q], 0, 0, 0);
            #pragma unroll
            for (int q = 0; q < 4; ++q)
                xacc[q] = __builtin_amdgcn_mfma_f32_16x16x32_bf16(
                    a1, wfx[q][s0 + 1], xacc[q], 0, 0, 0);
        };
        auto xmfma1 = [&](const int SLrd) {
            short8 a0 = *reinterpret_cast<const short8*>(&a_lds[SLrd + aoffX[0]]);
            #pragma unroll
            for (int q = 0; q < 4; ++q)
                xacc[q] = __builtin_amdgcn_mfma_f32_16x16x32_bf16(
                    a0, wfx[q][0], xacc[q], 0, 0, 0);
        };
        auto xgwrite = [&](const int XGP) {
            #pragma unroll
            for (int q = 0; q < 4; ++q) {
                float2 lo = {xacc[q][0], xacc[q][1]};
                float2 hi = {xacc[q][2], xacc[q][3]};
                *reinterpret_cast<float2*>(&a_lds[XGP + xgw[q]])        = lo;
                *reinterpret_cast<float2*>(&a_lds[XGP + PARS + xgw[q]]) = hi;
            }
        };

        // pair 0 xg (from SL0) into pair-buffer 0
        xinit();
        if constexpr (!IS_L0) { xmfma2(SL0, 0); xmfma2(SL0, 2); }
        else xmfma1(SL0);
        xgwrite(0);
        block_sync_lds();

        short4v xpre = {0, 0, 0, 0};
        float2  xpf  = {0.f, 0.f};

        auto xstepE = [&](int t, const int SLrd) {
            if (WRITE_H && t > 0) {
                unsigned int hv = *reinterpret_cast<const unsigned int*>(&a_lds[0 + hroff4]);
                *reinterpret_cast<unsigned int*>(&hbuf[(size_t)(t - 1) * BH + sgoff4]) = hv;
            }
            if constexpr (!IS_L0) {
                int tl = t + 4 + ss;  tl = tl < T_STEPS ? tl : T_STEPS - 1;
                xpre = *reinterpret_cast<const short4v*>(&hbuf[(size_t)tl * BH + xgrow]);
            } else if (xvalid) {
                int tl = t + 4 + ssL;  tl = tl < T_STEPS ? tl : T_STEPS - 1;
                xpf = *reinterpret_cast<const float2*>(&x0[x0row + (size_t)tl * 24]);
            }
            xinit();
            if constexpr (!IS_L0) xmfma2(SLrd, 0);
            else xmfma1(SLrd);
            block_sync_lds();
        };
        auto xstepO = [&](int t, const int SLrd, const int SLwr, const int XGP) {
            if (WRITE_H) {
                unsigned int hv = *reinterpret_cast<const unsigned int*>(&a_lds[HB + hroff4]);
                *reinterpret_cast<unsigned int*>(&hbuf[(size_t)(t - 1) * BH + sgoff4]) = hv;
            }
            if constexpr (!IS_L0)
                *reinterpret_cast<short4v*>(&a_lds[SLwr + xwoff]) = xpre;
            else if (xvalid) {
                unsigned int p;
                asm("v_cvt_pk_bf16_f32 %0, %1, %2" : "=v"(p) : "v"(xpf.x), "v"(xpf.y));
                *reinterpret_cast<unsigned int*>(&a_lds[SLwr + xw0off]) = p;
            }
            if constexpr (!IS_L0) xmfma2(SLrd, 2);
            xgwrite(XGP);
            block_sync_lds();
        };

        for (int mm = 0; mm < T_STEPS / 4; ++mm) {
            const int t0 = 4 * mm;
            xstepE(t0,     SL1);                  // build pair(2mm+1) slices 0,1
            xstepO(t0 + 1, SL1, SL0, PAIRS);      // slices 2,3 + write pair-buf 1
            xstepE(t0 + 2, SL0);                  // build pair(2mm+2) slices 0,1
            xstepO(t0 + 3, SL0, SL1, 0);          // slices 2,3 + write pair-buf 0
        }
        // h(255) writeback (sits in h buffer 0)
        if (WRITE_H) {
            unsigned int hv = *reinterpret_cast<const unsigned int*>(&a_lds[0 + hroff4]);
            *reinterpret_cast<unsigned int*>(&hbuf[(size_t)(T_STEPS - 1) * BH + sgoff4]) = hv;
        }
    }

    // fused final FC: out[b] = h_255[b] . Wfc + bfc  (h(255) in h buffer 0)
    if (FINAL && tid < 128) {
        const int r = tid >> 4, seg = tid & 15;
        float s = 0.f;
        #pragma unroll
        for (int k = 0; k < 8; ++k) {
            const int j = seg * 8 + k;
            s += bf2f(*reinterpret_cast<const unsigned short*>(&a_lds[lposH(r, 2 * j)]))
                 * Wfc[j];
        }
        #pragma unroll
        for (int off = 8; off >= 1; off >>= 1) s += __shfl_xor(s, off);
        if (seg == 0) out[b0 + r] = s + bfc[0];
    }
}

// All 3 layers fused (block-local layer sequencing; hbuf rows are private).
__global__ __launch_bounds__(1024, 4)
void lstm3(const float* __restrict__ x0,
           const float* __restrict__ Wih0, const float* __restrict__ Whh0,
           const float* __restrict__ bih0, const float* __restrict__ bhh0,
           const float* __restrict__ Wih1, const float* __restrict__ Whh1,
           const float* __restrict__ bih1, const float* __restrict__ bhh1,
           const float* __restrict__ Wih2, const float* __restrict__ Whh2,
           const float* __restrict__ bih2, const float* __restrict__ bhh2,
           const float* __restrict__ Wfc,  const float* __restrict__ bfc,
           unsigned short* __restrict__ hbuf, float* __restrict__ out)
{
    __shared__ __attribute__((aligned(16))) unsigned char a_lds[LDS_BYTES];
    const int tid = threadIdx.x;
    const int b0  = blockIdx.x * 8;

    lstm_phase<true,  true,  false>(a_lds, x0, Wih0, Whh0, bih0, bhh0, hbuf,
                                    nullptr, nullptr, nullptr, tid, b0);
    __syncthreads();
    lstm_phase<false, true,  false>(a_lds, nullptr, Wih1, Whh1, bih1, bhh1, hbuf,
                                    nullptr, nullptr, nullptr, tid, b0);
    __syncthreads();
    lstm_phase<false, false, true >(a_lds, nullptr, Wih2, Whh2, bih2, bhh2, hbuf,
                                    Wfc, bfc, out, tid, b0);
}

extern "C" void kernel_launch(void* const* d_in, const int* in_sizes, int n_in,
                              void* d_out, int out_size, void* d_ws, size_t ws_size,
                              hipStream_t stream) {
    (void)in_sizes; (void)n_in; (void)out_size; (void)ws_size;
    const float* x    = (const float*)d_in[0];
    const float* Wih0 = (const float*)d_in[1];
    const float* Whh0 = (const float*)d_in[2];
    const float* bih0 = (const float*)d_in[3];
    const float* bhh0 = (const float*)d_in[4];
    const float* Wih1 = (const float*)d_in[5];
    const float* Whh1 = (const float*)d_in[6];
    const float* bih1 = (const float*)d_in[7];
    const float* bhh1 = (const float*)d_in[8];
    const float* Wih2 = (const float*)d_in[9];
    const float* Whh2 = (const float*)d_in[10];
    const float* bih2 = (const float*)d_in[11];
    const float* bhh2 = (const float*)d_in[12];
    const float* Wfc  = (const float*)d_in[13];
    const float* bfc  = (const float*)d_in[14];
    float* out = (float*)d_out;
    unsigned short* hbuf = (unsigned short*)d_ws;   // [256][2048][128] bf16 = 134 MB

    dim3 grid(BATCH / 8), block(1024);
    lstm3<<<grid, block, 0, stream>>>(x, Wih0, Whh0, bih0, bhh0,
                                      Wih1, Whh1, bih1, bhh1,
                                      Wih2, Whh2, bih2, bhh2,
                                      Wfc, bfc, hbuf, out);
}

// Round 17
// 549.191 us; speedup vs baseline: 1.0238x; 1.0238x over previous
//
#include <hip/hip_runtime.h>

#define T_STEPS 256
#define BATCH   2048
#define HID     128
#define BH      (BATCH * HID)

typedef short short8  __attribute__((ext_vector_type(8)));
typedef short short4v __attribute__((ext_vector_type(4)));
typedef float float4v __attribute__((ext_vector_type(4)));

__device__ __forceinline__ unsigned short f2bf(float f) {
    unsigned int u = __builtin_bit_cast(unsigned int, f);
    u += 0x7fffu + ((u >> 16) & 1u);
    return (unsigned short)(u >> 16);
}
__device__ __forceinline__ float bf2f(unsigned short b) {
    unsigned int u = ((unsigned int)b) << 16;
    return __builtin_bit_cast(float, u);
}

#if __has_builtin(__builtin_amdgcn_exp2f)
#define EXP2F(x) __builtin_amdgcn_exp2f(x)
#else
#define EXP2F(x) exp2f(x)
#endif
__device__ __forceinline__ float sigf(float x) {
    return __builtin_amdgcn_rcpf(1.0f + EXP2F(x * -1.442695041f));
}
__device__ __forceinline__ float tanh_fast(float x) {
    return 2.0f * __builtin_amdgcn_rcpf(1.0f + EXP2F(x * -2.885390082f)) - 1.0f;
}

// Raw barrier without the vmcnt(0) drain of __syncthreads().
__device__ __forceinline__ void block_sync_lds() {
    asm volatile("s_waitcnt lgkmcnt(0)" ::: "memory");
    __builtin_amdgcn_s_barrier();
    __builtin_amdgcn_sched_barrier(0);
}

// h buffer: [8 rows][256 B], XOR-swizzled, 16-B granule.
__device__ __forceinline__ int lposH(int row, int off) {
    return row * 256 + (off ^ ((row & 7) << 4));
}
// x slot (L1/2): [16 rows][256 B]
__device__ __forceinline__ int lposX(int row, int off) {
    return row * 256 + (off ^ ((row & 7) << 4));
}
// x slot (L0): [16 rows][64 B]
__device__ __forceinline__ int lposX0(int row, int off) {
    return row * 64 + (off ^ ((row & 3) << 4));
}
// xg handoff: fp32 [par][q][row2(4)][col(128)][2] — the (row0,row0+1) pair a
// thread consumes is ONE b64. Bank check (32-lane halves): lanes 0-15
// (row2=0) claim dwords col*2,col*2+1 = banks 0-31 once; lanes 16-31
// (row2=2, base multiple of 128B) claim banks 0-31 once -> 2 claims/bank =
// b64 floor, conflict-free (verified r15: conflicts 60M -> 12M).
__device__ __forceinline__ int lposG(int q, int row0, int col) {
    return (q * 4 + (row0 >> 1)) * 1024 + col * 8;
}

__device__ __forceinline__ short8 load_w8(const float* __restrict__ p) {
    float4v a = *reinterpret_cast<const float4v*>(p);
    float4v b = *reinterpret_cast<const float4v*>(p + 4);
    short8 r;
    r[0] = (short)f2bf(a[0]); r[1] = (short)f2bf(a[1]);
    r[2] = (short)f2bf(a[2]); r[3] = (short)f2bf(a[3]);
    r[4] = (short)f2bf(b[0]); r[5] = (short)f2bf(b[1]);
    r[6] = (short)f2bf(b[2]); r[7] = (short)f2bf(b[3]);
    return r;
}

// LDS: [h0 2K][h1 2K][slot0][slot1][xg 64K]; max (L1/2) = 12288 + 65536
#define LDS_BYTES 77824

// 16-wave producer/consumer LSTM layer phase (block=1024, grid=256, 1/CU).
// 8 gate waves: h-MFMA only, 2 cells/thread. 8 x waves: slot staging,
// x-projection one pair ahead, xg handoff (b64 pairs), h->global writeback.
// wfh / wfx = 64 VGPR each -> 16 waves/CU (4/SIMD: 2 gate + 2 x).
template<bool IS_L0, bool WRITE_H, bool FINAL>
__device__ __forceinline__ void lstm_phase(
    unsigned char* a_lds,
    const float* __restrict__ x0,
    const float* __restrict__ Wih,
    const float* __restrict__ Whh,
    const float* __restrict__ bih,
    const float* __restrict__ bhh,
    unsigned short* __restrict__ hbuf,
    const float* __restrict__ Wfc,
    const float* __restrict__ bfc,
    float* __restrict__ out,
    const int tid, const int b0)
{
    constexpr int XKS = IS_L0 ? 1 : 4;               // x K-slices per pair
    constexpr int XRB = IS_L0 ? 64 : 256;            // x slot row bytes
    constexpr int HB  = 2048;
    constexpr int XB  = 16 * XRB;
    constexpr int SL0 = 2 * HB;
    constexpr int SL1 = 2 * HB + XB;
    constexpr int XGB = 2 * HB + 2 * XB;             // xg base
    constexpr int PARS  = 16384;                     // parity stride
    constexpr int PAIRS = 32768;                     // pair stride

    const int lane  = tid & 63;
    const int wv    = tid >> 6;                      // 0..15
    const int t16   = lane & 15;
    const int kgrp8 = (lane >> 4) * 8;
    const int row0  = ((lane >> 4) & 1) * 4 + ((lane >> 5) & 1) * 2;

    // zero h buffers + x slots (h(-1)=0; L0 pad cols stay 0)
    {
        short8 z = {0,0,0,0,0,0,0,0};
        for (int a = tid * 16; a < 2 * HB + 2 * XB; a += 1024 * 16)
            *reinterpret_cast<short8*>(&a_lds[a]) = z;
    }
    __syncthreads();

    if (tid < 512) {
        // ================= GATE WAVES (0-7) =================
        const int jcol = 16 * wv + t16;              // owned column
        const int g2 = t16 >> 2;
        const int hrow = ((g2 & 1) << 2) | ((g2 >> 1) << 1) | (t16 & 1);
        int aoffH[4];
        #pragma unroll
        for (int ks = 0; ks < 4; ++ks)
            aoffH[ks] = lposH(hrow, ks * 64 + kgrp8 * 2);
        const int hwoff0 = lposH(row0,     2 * jcol);
        const int hwoff1 = lposH(row0 + 1, 2 * jcol);
        int xgr[4];
        #pragma unroll
        for (int q = 0; q < 4; ++q)
            xgr[q] = XGB + lposG(q, row0, jcol);

        short8 wfh[4][4];
        #pragma unroll
        for (int q = 0; q < 4; ++q) {
            const int n = 128 * q + jcol;
            #pragma unroll
            for (int ks = 0; ks < 4; ++ks)
                wfh[q][ks] = load_w8(Whh + n * 128 + ks * 32 + kgrp8);
        }

        float cr0 = 0.f, cr1 = 0.f;
        block_sync_lds();               // pairs with x staging barrier
        block_sync_lds();               // pairs with x pair-0 barrier

        auto hstep = [&](const int rb, const int wb, const int xgo) {
            short8 hva[4];
            #pragma unroll
            for (int ks = 0; ks < 4; ++ks)
                hva[ks] = *reinterpret_cast<const short8*>(&a_lds[rb + aoffH[ks]]);
            float4v acc[4];
            #pragma unroll
            for (int q = 0; q < 4; ++q) {
                const float2 v = *reinterpret_cast<const float2*>(&a_lds[xgo + xgr[q]]);
                acc[q] = float4v{v.x, v.y, v.x, v.y};
            }
            __builtin_amdgcn_s_setprio(1);
            #pragma unroll
            for (int ks = 0; ks < 4; ++ks)
                #pragma unroll
                for (int q = 0; q < 4; ++q)
                    acc[q] = __builtin_amdgcn_mfma_f32_16x16x32_bf16(
                        hva[ks], wfh[q][ks], acc[q], 0, 0, 0);
            __builtin_amdgcn_s_setprio(0);
            const float c0 = sigf(acc[1][0]) * cr0 + sigf(acc[0][0]) * tanh_fast(acc[2][0]);
            const float c1 = sigf(acc[1][1]) * cr1 + sigf(acc[0][1]) * tanh_fast(acc[2][1]);
            cr0 = c0;  cr1 = c1;
            const float h0 = sigf(acc[3][0]) * tanh_fast(c0);
            const float h1 = sigf(acc[3][1]) * tanh_fast(c1);
            unsigned int pk;
            asm("v_cvt_pk_bf16_f32 %0, %1, %2" : "=v"(pk) : "v"(h0), "v"(h1));
            *reinterpret_cast<unsigned short*>(&a_lds[wb + hwoff0]) =
                (unsigned short)(pk & 0xffffu);
            *reinterpret_cast<unsigned short*>(&a_lds[wb + hwoff1]) =
                (unsigned short)(pk >> 16);
            block_sync_lds();
        };

        for (int mm = 0; mm < T_STEPS / 4; ++mm) {
            hstep(0,  HB, 0);                 // t=4mm   : pair-buf0, par0
            hstep(HB, 0,  PARS);              // t=4mm+1 : pair-buf0, par1
            hstep(0,  HB, PAIRS);             // t=4mm+2 : pair-buf1, par0
            hstep(HB, 0,  PAIRS + PARS);      // t=4mm+3 : pair-buf1, par1
        }
    } else {
        // ================= X WAVES (8-15) =================
        const int wx = wv - 8;
        const int jX = 16 * wx + t16;                // mirrored column
        const int tid2 = tid - 512;                  // 0..511
        // h->global writeback: 512 thr x 4 B over 8 rows x 256 B
        const int sh_row = tid2 >> 6, sh_c = tid2 & 63;
        const int hroff4 = lposH(sh_row, sh_c * 4);
        const size_t sgoff4 = (size_t)(b0 + sh_row) * HID + sh_c * 2;    // shorts
        // slot staging (L1/2): 512 thr x 8 B over 16 tile-rows x 256 B
        const int sar = tid2 >> 5, sc8 = tid2 & 31;
        const int sb  = (sar & 1) | (((sar >> 3) & 1) << 1) | (((sar >> 2) & 1) << 2);
        const int ss  = (sar >> 1) & 1;
        const int xwoff = lposX(sar, sc8 * 8);
        const size_t xgrow = (size_t)(b0 + sb) * HID + sc8 * 4;          // shorts
        // slot staging (L0): first 256 of tid2, 4 B (2 bf16) each
        const int  tidL = tid2 & 255;
        const bool l0act = tid2 < 256;
        const int  sarL = tidL >> 4, sc16 = tidL & 15;
        const int  sbL = (sarL & 1) | (((sarL >> 3) & 1) << 1) | (((sarL >> 2) & 1) << 2);
        const int  ssL = (sarL >> 1) & 1;
        const bool xvalid = l0act && (sc16 < 12);
        const int  xw0off = lposX0(sarL, sc16 * 4);
        const size_t x0row = (size_t)(b0 + sbL) * (T_STEPS * 24) + sc16 * 2;

        int aoffX[XKS];
        #pragma unroll
        for (int s = 0; s < XKS; ++s)
            aoffX[s] = IS_L0 ? lposX0(t16, kgrp8 * 2)
                             : lposX(t16, s * 64 + kgrp8 * 2);
        int xgw[4];
        #pragma unroll
        for (int q = 0; q < 4; ++q)
            xgw[q] = XGB + lposG(q, row0, jX);

        short8 wfx[4][XKS];
        float  bias[4];
        #pragma unroll
        for (int q = 0; q < 4; ++q) {
            const int n = 128 * q + jX;
            bias[q] = bih[n] + bhh[n];
            if constexpr (IS_L0) {
                if (kgrp8 < 24) wfx[q][0] = load_w8(Wih + n * 24 + kgrp8);
                else { short8 z = {0,0,0,0,0,0,0,0}; wfx[q][0] = z; }
            } else {
                #pragma unroll
                for (int s = 0; s < 4; ++s)
                    wfx[q][s] = load_w8(Wih + n * 128 + s * 32 + kgrp8);
            }
        }

        // prologue staging: SL0 = {x(0),x(1)}, SL1 = {x(2),x(3)}
        if constexpr (!IS_L0) {
            short4v v0 = *reinterpret_cast<const short4v*>(&hbuf[(size_t)(0 + ss) * BH + xgrow]);
            short4v v1 = *reinterpret_cast<const short4v*>(&hbuf[(size_t)(2 + ss) * BH + xgrow]);
            *reinterpret_cast<short4v*>(&a_lds[SL0 + xwoff]) = v0;
            *reinterpret_cast<short4v*>(&a_lds[SL1 + xwoff]) = v1;
        } else if (xvalid) {
            float2 a = *reinterpret_cast<const float2*>(&x0[x0row + (size_t)(0 + ssL) * 24]);
            float2 b = *reinterpret_cast<const float2*>(&x0[x0row + (size_t)(2 + ssL) * 24]);
            unsigned int pa, pb;
            asm("v_cvt_pk_bf16_f32 %0, %1, %2" : "=v"(pa) : "v"(a.x), "v"(a.y));
            asm("v_cvt_pk_bf16_f32 %0, %1, %2" : "=v"(pb) : "v"(b.x), "v"(b.y));
            *reinterpret_cast<unsigned int*>(&a_lds[SL0 + xw0off]) = pa;
            *reinterpret_cast<unsigned int*>(&a_lds[SL1 + xw0off]) = pb;
        }
        block_sync_lds();

        float4v xacc[4];
        auto xinit = [&]() {
            #pragma unroll
            for (int q = 0; q < 4; ++q)
                xacc[q] = float4v{bias[q], bias[q], bias[q], bias[q]};
        };
        auto xmfma2 = [&](const int SLrd, const int s0) {
            short8 a0 = *reinterpret_cast<const short8*>(&a_lds[SLrd + aoffX[s0]]);
            short8 a1 = *reinterpret_cast<const short8*>(&a_lds[SLrd + aoffX[s0 + 1]]);
            #pragma unroll
            for (int q = 0; q < 4; ++q)
                xacc[q] = __builtin_amdgcn_mfma_f32_16x16x32_bf16(
                    a0, wfx[q][s0], xacc[q], 0, 0, 0);
            #pragma unroll
            for (int q = 0; q < 4; ++q)
                xacc[q] = __builtin_amdgcn_mfma_f32_16x16x32_bf16(
                    a1, wfx[q][s0 + 1], xacc[q], 0, 0, 0);
        };
        auto xmfma1 = [&](const int SLrd) {
            short8 a0 = *reinterpret_cast<const short8*>(&a_lds[SLrd + aoffX[0]]);
            #pragma unroll
            for (int q = 0; q < 4; ++q)
                xacc[q] = __builtin_amdgcn_mfma_f32_16x16x32_bf16(
                    a0, wfx[q][0], xacc[q], 0, 0, 0);
        };
        auto xgwrite = [&](const int XGP) {
            #pragma unroll
            for (int q = 0; q < 4; ++q) {
                float2 lo = {xacc[q][0], xacc[q][1]};
                float2 hi = {xacc[q][2], xacc[q][3]};
                *reinterpret_cast<float2*>(&a_lds[XGP + xgw[q]])        = lo;
                *reinterpret_cast<float2*>(&a_lds[XGP + PARS + xgw[q]]) = hi;
            }
        };

        // pair 0 xg (from SL0) into pair-buffer 0
        xinit();
        if constexpr (!IS_L0) { xmfma2(SL0, 0); xmfma2(SL0, 2); }
        else xmfma1(SL0);
        xgwrite(0);
        block_sync_lds();

        short4v xpre = {0, 0, 0, 0};
        float2  xpf  = {0.f, 0.f};

        auto xstepE = [&](int t, const int SLrd) {
            if (WRITE_H && t > 0) {
                unsigned int hv = *reinterpret_cast<const unsigned int*>(&a_lds[0 + hroff4]);
                *reinterpret_cast<unsigned int*>(&hbuf[(size_t)(t - 1) * BH + sgoff4]) = hv;
            }
            if constexpr (!IS_L0) {
                int tl = t + 4 + ss;  tl = tl < T_STEPS ? tl : T_STEPS - 1;
                xpre = *reinterpret_cast<const short4v*>(&hbuf[(size_t)tl * BH + xgrow]);
            } else if (xvalid) {
                int tl = t + 4 + ssL;  tl = tl < T_STEPS ? tl : T_STEPS - 1;
                xpf = *reinterpret_cast<const float2*>(&x0[x0row + (size_t)tl * 24]);
            }
            xinit();
            if constexpr (!IS_L0) xmfma2(SLrd, 0);
            else xmfma1(SLrd);
            block_sync_lds();
        };
        auto xstepO = [&](int t, const int SLrd, const int SLwr, const int XGP) {
            if (WRITE_H) {
                unsigned int hv = *reinterpret_cast<const unsigned int*>(&a_lds[HB + hroff4]);
                *reinterpret_cast<unsigned int*>(&hbuf[(size_t)(t - 1) * BH + sgoff4]) = hv;
            }
            if constexpr (!IS_L0)
                *reinterpret_cast<short4v*>(&a_lds[SLwr + xwoff]) = xpre;
            else if (xvalid) {
                unsigned int p;
                asm("v_cvt_pk_bf16_f32 %0, %1, %2" : "=v"(p) : "v"(xpf.x), "v"(xpf.y));
                *reinterpret_cast<unsigned int*>(&a_lds[SLwr + xw0off]) = p;
            }
            if constexpr (!IS_L0) xmfma2(SLrd, 2);
            xgwrite(XGP);
            block_sync_lds();
        };

        for (int mm = 0; mm < T_STEPS / 4; ++mm) {
            const int t0 = 4 * mm;
            xstepE(t0,     SL1);                  // build pair(2mm+1) slices 0,1
            xstepO(t0 + 1, SL1, SL0, PAIRS);      // slices 2,3 + write pair-buf 1
            xstepE(t0 + 2, SL0);                  // build pair(2mm+2) slices 0,1
            xstepO(t0 + 3, SL0, SL1, 0);          // slices 2,3 + write pair-buf 0
        }
        // h(255) writeback (sits in h buffer 0)
        if (WRITE_H) {
            unsigned int hv = *reinterpret_cast<const unsigned int*>(&a_lds[0 + hroff4]);
            *reinterpret_cast<unsigned int*>(&hbuf[(size_t)(T_STEPS - 1) * BH + sgoff4]) = hv;
        }
    }

    // fused final FC: out[b] = h_255[b] . Wfc + bfc  (h(255) in h buffer 0)
    if (FINAL && tid < 128) {
        const int r = tid >> 4, seg = tid & 15;
        float s = 0.f;
        #pragma unroll
        for (int k = 0; k < 8; ++k) {
            const int j = seg * 8 + k;
            s += bf2f(*reinterpret_cast<const unsigned short*>(&a_lds[lposH(r, 2 * j)]))
                 * Wfc[j];
        }
        #pragma unroll
        for (int off = 8; off >= 1; off >>= 1) s += __shfl_xor(s, off);
        if (seg == 0) out[b0 + r] = s + bfc[0];
    }
}

// All 3 layers fused (block-local layer sequencing; hbuf rows are private).
__global__ __launch_bounds__(1024, 4)
void lstm3(const float* __restrict__ x0,
           const float* __restrict__ Wih0, const float* __restrict__ Whh0,
           const float* __restrict__ bih0, const float* __restrict__ bhh0,
           const float* __restrict__ Wih1, const float* __restrict__ Whh1,
           const float* __restrict__ bih1, const float* __restrict__ bhh1,
           const float* __restrict__ Wih2, const float* __restrict__ Whh2,
           const float* __restrict__ bih2, const float* __restrict__ bhh2,
           const float* __restrict__ Wfc,  const float* __restrict__ bfc,
           unsigned short* __restrict__ hbuf, float* __restrict__ out)
{
    __shared__ __attribute__((aligned(16))) unsigned char a_lds[LDS_BYTES];
    const int tid = threadIdx.x;
    const int b0  = blockIdx.x * 8;

    lstm_phase<true,  true,  false>(a_lds, x0, Wih0, Whh0, bih0, bhh0, hbuf,
                                    nullptr, nullptr, nullptr, tid, b0);
    __syncthreads();
    lstm_phase<false, true,  false>(a_lds, nullptr, Wih1, Whh1, bih1, bhh1, hbuf,
                                    nullptr, nullptr, nullptr, tid, b0);
    __syncthreads();
    lstm_phase<false, false, true >(a_lds, nullptr, Wih2, Whh2, bih2, bhh2, hbuf,
                                    Wfc, bfc, out, tid, b0);
}

extern "C" void kernel_launch(void* const* d_in, const int* in_sizes, int n_in,
                              void* d_out, int out_size, void* d_ws, size_t ws_size,
                              hipStream_t stream) {
    (void)in_sizes; (void)n_in; (void)out_size; (void)ws_size;
    const float* x    = (const float*)d_in[0];
    const float* Wih0 = (const float*)d_in[1];
    const float* Whh0 = (const float*)d_in[2];
    const float* bih0 = (const float*)d_in[3];
    const float* bhh0 = (const float*)d_in[4];
    const float* Wih1 = (const float*)d_in[5];
    const float* Whh1 = (const float*)d_in[6];
    const float* bih1 = (const float*)d_in[7];
    const float* bhh1 = (const float*)d_in[8];
    const float* Wih2 = (const float*)d_in[9];
    const float* Whh2 = (const float*)d_in[10];
    const float* bih2 = (const float*)d_in[11];
    const float* bhh2 = (const float*)d_in[12];
    const float* Wfc  = (const float*)d_in[13];
    const float* bfc  = (const float*)d_in[14];
    float* out = (float*)d_out;
    unsigned short* hbuf = (unsigned short*)d_ws;   // [256][2048][128] bf16 = 134 MB

    dim3 grid(BATCH / 8), block(1024);
    lstm3<<<grid, block, 0, stream>>>(x, Wih0, Whh0, bih0, bhh0,
                                      Wih1, Whh1, bih1, bhh1,
                                      Wih2, Whh2, bih2, bhh2,
                                      Wfc, bfc, hbuf, out);
}